// Round 7
// baseline (142.227 us; speedup 1.0000x reference)
//
#include <hip/hip_runtime.h>
#include <math.h>

#define G 512
#define N 400
#define D 128
#define K 200
#define DOUT 512
#define DMID 32
#define GK (G*K)      // 102400
#define KD (K*D)      // 25600

#define SH  129       // sHt stride (GEMM2)
#define SW2 36        // padded stride for W2T tile (GEMM2)

#define KQ 25         // clusters per fused block (grid (8,G))

__device__ __forceinline__ float relu(float v) { return fmaxf(v, 0.0f); }

typedef __attribute__((ext_vector_type(8))) short short8b;   // 8 bf16 = 4 VGPR
typedef __attribute__((ext_vector_type(16))) float floatx16; // mfma 32x32 acc

__device__ __forceinline__ ushort f2bf(float f) {  // fp32 -> bf16 (RNE)
  unsigned u = __float_as_uint(f);
  unsigned r = (u + 0x7FFFu + ((u >> 16) & 1u)) >> 16;
  return (ushort)r;
}
__device__ __forceinline__ float bf2f(ushort h) {
  return __uint_as_float(((unsigned)h) << 16);
}

// Native global fp32 atomic add (inline asm: HIP's atomicAdd(float*) may lower
// to a CAS retry loop without -munsafe-fp-atomics; the native op has no retry).
__device__ __forceinline__ void gl_fadd(float* p, float v) {
  asm volatile("global_atomic_add_f32 %0, %1, off"
               :
               : "v"(p), "v"(v)
               : "memory");
}

// ---------------- K1b: W1 -> fragment-major hi/lo bf16 + workspace zeroing ----------------
// Blocks 0..63: W1 prep. Block 64: zero h2pre + out (stream-ordered before
// gemm2_partial's atomics; re-zeroed every iteration).
__global__ __launch_bounds__(256) void w1prep(
    const float* __restrict__ W1, ushort* __restrict__ wh, ushort* __restrict__ wl,
    float* __restrict__ h2pre, float* __restrict__ out) {
  if (blockIdx.x == 64) {
    for (int i = threadIdx.x; i < G * DMID; i += 256) h2pre[i] = 0.0f;
    if (threadIdx.x == 0) out[0] = 0.0f;
    return;
  }
  const int idx = blockIdx.x * 256 + threadIdx.x;  // < 16384
  const int i = idx & 7, l = (idx >> 3) & 63, ks = (idx >> 9) & 7, nt = idx >> 12;
  const int k = ks * 16 + (l >> 5) * 8 + i;
  const int n = nt * 32 + (l & 31);
  const float v = W1[k * D + n];
  const ushort h = f2bf(v);
  wh[idx] = h;
  wl[idx] = f2bf(v - bf2f(h));
}

// ---------------- K1: FUSED pool + GEMM1, 25-cluster blocks, 8 blocks/CU ----------------
// Block = (g, 25-cluster octant), grid (8,G)=4096. Phase A: bucket-sort rows,
// gather-mean (batched 8-deep pipelined loads), flush rows as hi/lo bf16 frags
// into ONE 32-row m-tile (XOR-ks swizzle; rows 25..31 pre-zeroed). Scan = one
// wave-0 shfl_up pass. Phase B: 24 MFMAs, scatter epilogue. ~20 KB LDS.
// VERIFIED at ~58.4 us — do not restructure without a counter-backed theory.
__global__ __launch_bounds__(256) void pool_gemm1_fused(
    const float* __restrict__ x, const int* __restrict__ cluster,
    const ushort* __restrict__ wh, const ushort* __restrict__ wl,
    const float* __restrict__ b1, float* __restrict__ h1) {
  __shared__ int s_ids[N];
  __shared__ int s_cnt[KQ];
  __shared__ int s_off[KQ + 1];
  __shared__ int s_cur[KQ];
  __shared__ int s_sorted[N];           // packed (local_id<<9)|row
  __shared__ ushort sAhi[8 * 64 * 8];   // [ks][slot^ks][i], 8 KB
  __shared__ ushort sAlo[8 * 64 * 8];
  const int g = blockIdx.y;
  const int kb = blockIdx.x * KQ;
  const int tid = threadIdx.x;
  const int* cg = cluster + g * N;

  for (int i = tid; i < N; i += 256) s_ids[i] = cg[i];
  if (tid < KQ) { s_cnt[tid] = 0; s_cur[tid] = 0; }
  {
    short8b z;
#pragma unroll
    for (int e = 0; e < 8; ++e) z[e] = 0;
    for (int i = tid; i < 512; i += 256) {
      *(short8b*)&sAhi[i * 8] = z;
      *(short8b*)&sAlo[i * 8] = z;
    }
  }
  __syncthreads();

  for (int i = tid; i < N; i += 256) {
    const int id = s_ids[i] - kb;
    if ((unsigned)id < (unsigned)KQ) atomicAdd(&s_cnt[id], 1);
  }
  __syncthreads();

  // wave-0 inclusive scan over KQ=25 counts (shfl_up, no block barriers)
  if (tid < 64) {
    const int cv = (tid < KQ) ? s_cnt[tid] : 0;
    int c = cv;
#pragma unroll
    for (int off = 1; off < 32; off <<= 1) {
      const int t = __shfl_up(c, off);
      if (tid >= off) c += t;
    }
    if (tid < KQ) s_off[tid] = c - cv;   // exclusive
    if (tid == KQ - 1) s_off[KQ] = c;
  }
  __syncthreads();

  for (int i = tid; i < N; i += 256) {
    const int id = s_ids[i] - kb;
    if ((unsigned)id < (unsigned)KQ) {
      const int pos = atomicAdd(&s_cur[id], 1);
      s_sorted[s_off[id] + pos] = (id << 9) | i;
    }
  }
  __syncthreads();

  // ---- Phase A gather: wave wv owns clusters [(wv*25)>>2, ((wv+1)*25)>>2) ----
  const int wv = tid >> 6, l = tid & 63;
  {
    const int kl0 = (wv * KQ) >> 2;
    const int kl1 = ((wv + 1) * KQ) >> 2;
    const float* xg = x + (size_t)g * N * D + l * 2;
    // frag-position constants for this lane's k-pair (k0 = 2l, k0+1)
    const int k0 = 2 * l;
    const int ksL = k0 >> 4, kqL = (k0 >> 3) & 1, i0 = k0 & 7;

#define PL_FLUSH(KL, AX, AY, INV)                                          \
    {                                                                      \
      const int blk = ksL * 64 + ((kqL * 32 + (KL)) ^ ksL);                \
      const float fx = (AX) * (INV), fy = (AY) * (INV);                    \
      const ushort hx = f2bf(fx), hy = f2bf(fy);                           \
      ushort2 hv; hv.x = hx; hv.y = hy;                                    \
      ushort2 lv;                                                          \
      lv.x = f2bf(fx - bf2f(hx)); lv.y = f2bf(fy - bf2f(hy));              \
      *(ushort2*)&sAhi[blk * 8 + i0] = hv;                                 \
      *(ushort2*)&sAlo[blk * 8 + i0] = lv;                                 \
    }

    if (kl1 > kl0) {
      const int i0g = s_off[kl0], i1g = s_off[kl1];
      if (i1g > i0g) {
        int prev = -1;
        float ax = 0.0f, ay = 0.0f;
        int pkA[8], pkB[8];
        float2 vA[8], vB[8];

#define PL_LOAD(PK, VV, BASE)                                              \
        {                                                                  \
          _Pragma("unroll")                                                \
          for (int j = 0; j < 8; ++j) {                                    \
            const int mi = ((BASE) + j < i1g) ? (BASE) + j : i1g - 1;      \
            PK[j] = s_sorted[mi];                                          \
          }                                                                \
          _Pragma("unroll")                                                \
          for (int j = 0; j < 8; ++j)                                      \
            VV[j] = *(const float2*)&xg[(size_t)(PK[j] & 511) * D];        \
        }

#define PL_PROC(PK, VV, BASE)                                              \
        {                                                                  \
          _Pragma("unroll")                                                \
          for (int j = 0; j < 8; ++j) {                                    \
            if ((BASE) + j < i1g) {                                        \
              const int id = PK[j] >> 9;                                   \
              if (id != prev) {                                            \
                if (prev >= 0) {                                           \
                  const float inv = 1.0f / (float)s_cnt[prev];             \
                  PL_FLUSH(prev, ax, ay, inv);                             \
                }                                                          \
                ax = VV[j].x; ay = VV[j].y; prev = id;                     \
              } else { ax += VV[j].x; ay += VV[j].y; }                     \
            }                                                              \
          }                                                                \
        }

        int base = i0g;
        PL_LOAD(pkA, vA, base);
        while (base < i1g) {
          if (base + 8 < i1g) PL_LOAD(pkB, vB, base + 8);
          PL_PROC(pkA, vA, base);
          base += 8;
          if (base >= i1g) break;
          if (base + 8 < i1g) PL_LOAD(pkA, vA, base + 8);
          PL_PROC(pkB, vB, base);
          base += 8;
        }
        if (prev >= 0) {
          const float inv = 1.0f / (float)s_cnt[prev];
          PL_FLUSH(prev, ax, ay, inv);
        }
#undef PL_LOAD
#undef PL_PROC
      }
    }
#undef PL_FLUSH
  }
  __syncthreads();

  // ---- Phase B: split-bf16 MFMA, wave wv owns n-tile [wv*32, wv*32+32) ----
  floatx16 acc0;
#pragma unroll
  for (int e = 0; e < 16; ++e) acc0[e] = 0.0f;

  const ushort* whw = wh + (size_t)(wv * 8) * 64 * 8;
  const ushort* wlw = wl + (size_t)(wv * 8) * 64 * 8;

#pragma unroll 2
  for (int ks = 0; ks < 8; ++ks) {
    const int lx = l ^ ks;  // read-side of the write swizzle
    const short8b bh = *(const short8b*)&whw[(ks * 64 + l) * 8];
    const short8b bl = *(const short8b*)&wlw[(ks * 64 + l) * 8];
    const short8b ah = *(const short8b*)&sAhi[(ks * 64 + lx) * 8];
    const short8b al = *(const short8b*)&sAlo[(ks * 64 + lx) * 8];
    acc0 = __builtin_amdgcn_mfma_f32_32x32x16_bf16(ah, bh, acc0, 0, 0, 0);
    acc0 = __builtin_amdgcn_mfma_f32_32x32x16_bf16(ah, bl, acc0, 0, 0, 0);
    acc0 = __builtin_amdgcn_mfma_f32_32x32x16_bf16(al, bh, acc0, 0, 0, 0);
  }

  // epilogue: C/D layout col=lane&31, row=(e&3)+8*(e>>2)+4*(lane>>5)
  const int col = l & 31;
  const int n = wv * 32 + col;
  const float bias = b1[n];
  const int rbase = 4 * (l >> 5);
  float* hrow = h1 + ((size_t)g * K + kb) * D + n;
#pragma unroll
  for (int e = 0; e < 16; ++e) {
    const int row = (e & 3) + 8 * (e >> 2) + rbase;
    if (row < KQ) hrow[(size_t)row * D] = relu(acc0[e] + bias);
  }
}

// ---------------- K3: GEMM2 partials -> atomic accumulate into h2pre ----------------
// grid (200, 16). Output path: the 32x32 block result is added directly to
// h2pre with native f32 atomics (64 distinct addresses per wave-instr,
// <=200-way contention per address spread over the kernel). Removes the
// partials 26 MB round-trip and the reduce kernel + its launch.
__global__ __launch_bounds__(256) void gemm2_partial(
    const float* __restrict__ h1, const float* __restrict__ W2,
    float* __restrict__ h2pre) {
  extern __shared__ float smem[];
  float* sHt = smem;             // [32][SH]
  float* sWT = smem + 32 * SH;   // [128][SW2]
  const int kc = blockIdx.x;     // 0..199
  const int gb = blockIdx.y;     // 0..15
  const int k0 = kc * 128, g0 = gb * 32;
  const int tid = threadIdx.x;

  for (int i = tid; i < 32 * 128; i += 256) {
    const int r = i >> 7, k = i & 127;
    sHt[r * SH + k] = h1[(size_t)(g0 + r) * KD + k0 + k];
  }
  for (int i = tid; i < 32 * 128; i += 256) {
    const int j = i >> 7, k = i & 127;
    sWT[k * SW2 + j] = W2[(size_t)j * KD + k0 + k];
  }
  __syncthreads();

  const int jt = tid & 7;   // j block of 4
  const int gt = tid >> 3;  // one g row each (32)
  float acc[4];
#pragma unroll
  for (int j = 0; j < 4; j++) acc[j] = 0.0f;

  for (int k = 0; k < 128; ++k) {
    const float h = sHt[gt * SH + k];
    const float4 w0 = *(const float4*)&sWT[k * SW2 + jt * 4];
    acc[0] = fmaf(h, w0.x, acc[0]); acc[1] = fmaf(h, w0.y, acc[1]);
    acc[2] = fmaf(h, w0.z, acc[2]); acc[3] = fmaf(h, w0.w, acc[3]);
  }

  float* pp = h2pre + (size_t)(g0 + gt) * DMID + jt * 4;
  gl_fadd(&pp[0], acc[0]);
  gl_fadd(&pp[1], acc[1]);
  gl_fadd(&pp[2], acc[2]);
  gl_fadd(&pp[3], acc[3]);
}

// ---------------- K5: GEMM3 + cosine + squared error -> atomic mean ----------------
// Reads h2pre (pre-bias accumulator), applies relu(v+b2) on load; adds
// e^2/256 straight into out[0] (zeroed by w1prep). Replaces head+loss pair.
__global__ __launch_bounds__(256) void head_kernel(
    const float* __restrict__ h2pre, const float* __restrict__ b2,
    const float* __restrict__ W3, const float* __restrict__ b3,
    const float* __restrict__ ts, float* __restrict__ out) {
  __shared__ float sA[DMID], sB[DMID];
  __shared__ float rdot[4], rna[4], rnb[4];
  const int p = blockIdx.x;
  const int tid = threadIdx.x;
  if (tid < DMID)
    sA[tid] = relu(h2pre[(size_t)(2 * p) * DMID + tid] + b2[tid]);
  else if (tid < 2 * DMID)
    sB[tid - DMID] = relu(h2pre[(size_t)(2 * p + 1) * DMID + (tid - DMID)] + b2[tid - DMID]);
  __syncthreads();

  float dot = 0.0f, na = 0.0f, nb = 0.0f;
#pragma unroll
  for (int rep = 0; rep < 2; ++rep) {
    const int o = rep * 256 + tid;
    const float* w = W3 + (size_t)o * DMID;
    float accA = b3[o], accB = accA;
#pragma unroll
    for (int m = 0; m < DMID; m += 4) {
      const float4 wv = *(const float4*)&w[m];
      accA = fmaf(sA[m], wv.x, accA); accB = fmaf(sB[m], wv.x, accB);
      accA = fmaf(sA[m + 1], wv.y, accA); accB = fmaf(sB[m + 1], wv.y, accB);
      accA = fmaf(sA[m + 2], wv.z, accA); accB = fmaf(sB[m + 2], wv.z, accB);
      accA = fmaf(sA[m + 3], wv.w, accA); accB = fmaf(sB[m + 3], wv.w, accB);
    }
    const float a = relu(accA), b = relu(accB);
    dot = fmaf(a, b, dot); na = fmaf(a, a, na); nb = fmaf(b, b, nb);
  }
#pragma unroll
  for (int off = 32; off >= 1; off >>= 1) {
    dot += __shfl_down(dot, off);
    na  += __shfl_down(na, off);
    nb  += __shfl_down(nb, off);
  }
  const int wave = tid >> 6, lane = tid & 63;
  if (lane == 0) { rdot[wave] = dot; rna[wave] = na; rnb[wave] = nb; }
  __syncthreads();
  if (tid == 0) {
    const float dt = rdot[0] + rdot[1] + rdot[2] + rdot[3];
    const float nA = rna[0] + rna[1] + rna[2] + rna[3];
    const float nB = rnb[0] + rnb[1] + rnb[2] + rnb[3];
    const float n1 = fmaxf(sqrtf(nA), 1e-6f);
    const float n2 = fmaxf(sqrtf(nB), 1e-6f);
    const float sc = dt / (n1 * n2);
    const float e = sc - ts[p];
    gl_fadd(out, e * e * (1.0f / 256.0f));
  }
}

extern "C" void kernel_launch(void* const* d_in, const int* in_sizes, int n_in,
                              void* d_out, int out_size, void* d_ws, size_t ws_size,
                              hipStream_t stream) {
  const float* x       = (const float*)d_in[0];
  const int*   cluster = (const int*)d_in[1];
  const float* ts      = (const float*)d_in[2];
  const float* W1      = (const float*)d_in[3];
  const float* b1      = (const float*)d_in[4];
  const float* W2      = (const float*)d_in[5];
  const float* b2      = (const float*)d_in[6];
  const float* W3      = (const float*)d_in[7];
  const float* b3      = (const float*)d_in[8];

  float* ws = (float*)d_ws;
  float* h1        = ws;                                   // GK*D
  float* h2pre     = h1 + (size_t)GK * D;                  // G*DMID
  ushort* wfrag_hi = (ushort*)(h2pre + (size_t)G * DMID);  // 16384 bf16
  ushort* wfrag_lo = wfrag_hi + 16384;                     // 16384 bf16
  float* out       = (float*)d_out;

  w1prep<<<65, 256, 0, stream>>>(W1, wfrag_hi, wfrag_lo, h2pre, out);
  dim3 gridP(8, G);
  pool_gemm1_fused<<<gridP, 256, 0, stream>>>(x, cluster, wfrag_hi, wfrag_lo, b1, h1);
  dim3 gridC(200, 16);
  gemm2_partial<<<gridC, 256, (32 * SH + 128 * SW2) * sizeof(float), stream>>>(h1, W2, h2pre);
  head_kernel<<<G / 2, 256, 0, stream>>>(h2pre, b2, W3, b3, ts, out);
}

// Round 8
// 91.187 us; speedup vs baseline: 1.5597x; 1.5597x over previous
//
#include <hip/hip_runtime.h>
#include <math.h>

#define G 512
#define N 400
#define D 128
#define K 200
#define DOUT 512
#define DMID 32
#define GK (G*K)      // 102400
#define KD (K*D)      // 25600
#define NCHUNK 200    // GEMM2 k-chunks of 128

#define SH  129       // sHt stride (GEMM2)
#define SW2 36        // padded stride for W2T tile (GEMM2)

#define KQ 25         // clusters per fused block (grid (8,G))

__device__ __forceinline__ float relu(float v) { return fmaxf(v, 0.0f); }

typedef __attribute__((ext_vector_type(8))) short short8b;   // 8 bf16 = 4 VGPR
typedef __attribute__((ext_vector_type(16))) float floatx16; // mfma 32x32 acc

__device__ __forceinline__ ushort f2bf(float f) {  // fp32 -> bf16 (RNE)
  unsigned u = __float_as_uint(f);
  unsigned r = (u + 0x7FFFu + ((u >> 16) & 1u)) >> 16;
  return (ushort)r;
}
__device__ __forceinline__ float bf2f(ushort h) {
  return __uint_as_float(((unsigned)h) << 16);
}

// Native global fp32 atomic add. Used ONLY for the 256 low-contention
// loss-term adds in head_kernel (round-7 lesson: NEVER for high-contention
// accumulation — 200-way per-address serialization cost +80 us).
__device__ __forceinline__ void gl_fadd(float* p, float v) {
  asm volatile("global_atomic_add_f32 %0, %1, off"
               :
               : "v"(p), "v"(v)
               : "memory");
}

// ---------------- K1b: W1 -> fragment-major hi/lo bf16 + out zeroing ----------------
// Blocks 0..63: W1 prep. Block 64: zero out[0] (stream-ordered before head's
// atomic loss accumulation; re-zeroed every iteration).
__global__ __launch_bounds__(256) void w1prep(
    const float* __restrict__ W1, ushort* __restrict__ wh, ushort* __restrict__ wl,
    float* __restrict__ out) {
  if (blockIdx.x == 64) {
    if (threadIdx.x == 0) out[0] = 0.0f;
    return;
  }
  const int idx = blockIdx.x * 256 + threadIdx.x;  // < 16384
  const int i = idx & 7, l = (idx >> 3) & 63, ks = (idx >> 9) & 7, nt = idx >> 12;
  const int k = ks * 16 + (l >> 5) * 8 + i;
  const int n = nt * 32 + (l & 31);
  const float v = W1[k * D + n];
  const ushort h = f2bf(v);
  wh[idx] = h;
  wl[idx] = f2bf(v - bf2f(h));
}

// ---------------- K1: FUSED pool + GEMM1, 25-cluster blocks, 8 blocks/CU ----------------
// Block = (g, 25-cluster octant), grid (8,G)=4096. Phase A: bucket-sort rows,
// gather-mean (batched 8-deep pipelined loads), flush rows as hi/lo bf16 frags
// into ONE 32-row m-tile (XOR-ks swizzle; rows 25..31 pre-zeroed). Scan = one
// wave-0 shfl_up pass. Phase B: 24 MFMAs, scatter epilogue. ~20 KB LDS.
// VERIFIED at ~58.4 us — do not restructure without a counter-backed theory.
__global__ __launch_bounds__(256) void pool_gemm1_fused(
    const float* __restrict__ x, const int* __restrict__ cluster,
    const ushort* __restrict__ wh, const ushort* __restrict__ wl,
    const float* __restrict__ b1, float* __restrict__ h1) {
  __shared__ int s_ids[N];
  __shared__ int s_cnt[KQ];
  __shared__ int s_off[KQ + 1];
  __shared__ int s_cur[KQ];
  __shared__ int s_sorted[N];           // packed (local_id<<9)|row
  __shared__ ushort sAhi[8 * 64 * 8];   // [ks][slot^ks][i], 8 KB
  __shared__ ushort sAlo[8 * 64 * 8];
  const int g = blockIdx.y;
  const int kb = blockIdx.x * KQ;
  const int tid = threadIdx.x;
  const int* cg = cluster + g * N;

  for (int i = tid; i < N; i += 256) s_ids[i] = cg[i];
  if (tid < KQ) { s_cnt[tid] = 0; s_cur[tid] = 0; }
  {
    short8b z;
#pragma unroll
    for (int e = 0; e < 8; ++e) z[e] = 0;
    for (int i = tid; i < 512; i += 256) {
      *(short8b*)&sAhi[i * 8] = z;
      *(short8b*)&sAlo[i * 8] = z;
    }
  }
  __syncthreads();

  for (int i = tid; i < N; i += 256) {
    const int id = s_ids[i] - kb;
    if ((unsigned)id < (unsigned)KQ) atomicAdd(&s_cnt[id], 1);
  }
  __syncthreads();

  // wave-0 inclusive scan over KQ=25 counts (shfl_up, no block barriers)
  if (tid < 64) {
    const int cv = (tid < KQ) ? s_cnt[tid] : 0;
    int c = cv;
#pragma unroll
    for (int off = 1; off < 32; off <<= 1) {
      const int t = __shfl_up(c, off);
      if (tid >= off) c += t;
    }
    if (tid < KQ) s_off[tid] = c - cv;   // exclusive
    if (tid == KQ - 1) s_off[KQ] = c;
  }
  __syncthreads();

  for (int i = tid; i < N; i += 256) {
    const int id = s_ids[i] - kb;
    if ((unsigned)id < (unsigned)KQ) {
      const int pos = atomicAdd(&s_cur[id], 1);
      s_sorted[s_off[id] + pos] = (id << 9) | i;
    }
  }
  __syncthreads();

  // ---- Phase A gather: wave wv owns clusters [(wv*25)>>2, ((wv+1)*25)>>2) ----
  const int wv = tid >> 6, l = tid & 63;
  {
    const int kl0 = (wv * KQ) >> 2;
    const int kl1 = ((wv + 1) * KQ) >> 2;
    const float* xg = x + (size_t)g * N * D + l * 2;
    // frag-position constants for this lane's k-pair (k0 = 2l, k0+1)
    const int k0 = 2 * l;
    const int ksL = k0 >> 4, kqL = (k0 >> 3) & 1, i0 = k0 & 7;

#define PL_FLUSH(KL, AX, AY, INV)                                          \
    {                                                                      \
      const int blk = ksL * 64 + ((kqL * 32 + (KL)) ^ ksL);                \
      const float fx = (AX) * (INV), fy = (AY) * (INV);                    \
      const ushort hx = f2bf(fx), hy = f2bf(fy);                           \
      ushort2 hv; hv.x = hx; hv.y = hy;                                    \
      ushort2 lv;                                                          \
      lv.x = f2bf(fx - bf2f(hx)); lv.y = f2bf(fy - bf2f(hy));              \
      *(ushort2*)&sAhi[blk * 8 + i0] = hv;                                 \
      *(ushort2*)&sAlo[blk * 8 + i0] = lv;                                 \
    }

    if (kl1 > kl0) {
      const int i0g = s_off[kl0], i1g = s_off[kl1];
      if (i1g > i0g) {
        int prev = -1;
        float ax = 0.0f, ay = 0.0f;
        int pkA[8], pkB[8];
        float2 vA[8], vB[8];

#define PL_LOAD(PK, VV, BASE)                                              \
        {                                                                  \
          _Pragma("unroll")                                                \
          for (int j = 0; j < 8; ++j) {                                    \
            const int mi = ((BASE) + j < i1g) ? (BASE) + j : i1g - 1;      \
            PK[j] = s_sorted[mi];                                          \
          }                                                                \
          _Pragma("unroll")                                                \
          for (int j = 0; j < 8; ++j)                                      \
            VV[j] = *(const float2*)&xg[(size_t)(PK[j] & 511) * D];        \
        }

#define PL_PROC(PK, VV, BASE)                                              \
        {                                                                  \
          _Pragma("unroll")                                                \
          for (int j = 0; j < 8; ++j) {                                    \
            if ((BASE) + j < i1g) {                                        \
              const int id = PK[j] >> 9;                                   \
              if (id != prev) {                                            \
                if (prev >= 0) {                                           \
                  const float inv = 1.0f / (float)s_cnt[prev];             \
                  PL_FLUSH(prev, ax, ay, inv);                             \
                }                                                          \
                ax = VV[j].x; ay = VV[j].y; prev = id;                     \
              } else { ax += VV[j].x; ay += VV[j].y; }                     \
            }                                                              \
          }                                                                \
        }

        int base = i0g;
        PL_LOAD(pkA, vA, base);
        while (base < i1g) {
          if (base + 8 < i1g) PL_LOAD(pkB, vB, base + 8);
          PL_PROC(pkA, vA, base);
          base += 8;
          if (base >= i1g) break;
          if (base + 8 < i1g) PL_LOAD(pkA, vA, base + 8);
          PL_PROC(pkB, vB, base);
          base += 8;
        }
        if (prev >= 0) {
          const float inv = 1.0f / (float)s_cnt[prev];
          PL_FLUSH(prev, ax, ay, inv);
        }
#undef PL_LOAD
#undef PL_PROC
      }
    }
#undef PL_FLUSH
  }
  __syncthreads();

  // ---- Phase B: split-bf16 MFMA, wave wv owns n-tile [wv*32, wv*32+32) ----
  floatx16 acc0;
#pragma unroll
  for (int e = 0; e < 16; ++e) acc0[e] = 0.0f;

  const ushort* whw = wh + (size_t)(wv * 8) * 64 * 8;
  const ushort* wlw = wl + (size_t)(wv * 8) * 64 * 8;

#pragma unroll 2
  for (int ks = 0; ks < 8; ++ks) {
    const int lx = l ^ ks;  // read-side of the write swizzle
    const short8b bh = *(const short8b*)&whw[(ks * 64 + l) * 8];
    const short8b bl = *(const short8b*)&wlw[(ks * 64 + l) * 8];
    const short8b ah = *(const short8b*)&sAhi[(ks * 64 + lx) * 8];
    const short8b al = *(const short8b*)&sAlo[(ks * 64 + lx) * 8];
    acc0 = __builtin_amdgcn_mfma_f32_32x32x16_bf16(ah, bh, acc0, 0, 0, 0);
    acc0 = __builtin_amdgcn_mfma_f32_32x32x16_bf16(ah, bl, acc0, 0, 0, 0);
    acc0 = __builtin_amdgcn_mfma_f32_32x32x16_bf16(al, bh, acc0, 0, 0, 0);
  }

  // epilogue: C/D layout col=lane&31, row=(e&3)+8*(e>>2)+4*(lane>>5)
  const int col = l & 31;
  const int n = wv * 32 + col;
  const float bias = b1[n];
  const int rbase = 4 * (l >> 5);
  float* hrow = h1 + ((size_t)g * K + kb) * D + n;
#pragma unroll
  for (int e = 0; e < 16; ++e) {
    const int row = (e & 3) + 8 * (e >> 2) + rbase;
    if (row < KQ) hrow[(size_t)row * D] = relu(acc0[e] + bias);
  }
}

// ---------------- K3: GEMM2 partials (32-row g-blocks) ----------------
__global__ __launch_bounds__(256) void gemm2_partial(
    const float* __restrict__ h1, const float* __restrict__ W2,
    float* __restrict__ partials) {
  extern __shared__ float smem[];
  float* sHt = smem;             // [32][SH]
  float* sWT = smem + 32 * SH;   // [128][SW2]
  const int kc = blockIdx.x;     // 0..199
  const int gb = blockIdx.y;     // 0..15
  const int k0 = kc * 128, g0 = gb * 32;
  const int tid = threadIdx.x;

  for (int i = tid; i < 32 * 128; i += 256) {
    const int r = i >> 7, k = i & 127;
    sHt[r * SH + k] = h1[(size_t)(g0 + r) * KD + k0 + k];
  }
  for (int i = tid; i < 32 * 128; i += 256) {
    const int j = i >> 7, k = i & 127;
    sWT[k * SW2 + j] = W2[(size_t)j * KD + k0 + k];
  }
  __syncthreads();

  const int jt = tid & 7;   // j block of 4
  const int gt = tid >> 3;  // one g row each (32)
  float acc[4];
#pragma unroll
  for (int j = 0; j < 4; j++) acc[j] = 0.0f;

  for (int k = 0; k < 128; ++k) {
    const float h = sHt[gt * SH + k];
    const float4 w0 = *(const float4*)&sWT[k * SW2 + jt * 4];
    acc[0] = fmaf(h, w0.x, acc[0]); acc[1] = fmaf(h, w0.y, acc[1]);
    acc[2] = fmaf(h, w0.z, acc[2]); acc[3] = fmaf(h, w0.w, acc[3]);
  }

  float* pp = partials + ((size_t)kc * G + g0 + gt) * DMID + jt * 4;
  *(float4*)&pp[0] = make_float4(acc[0], acc[1], acc[2], acc[3]);
}

// ---------------- K4: fused reduce (200 -> h2), grid 256 x 256 ----------------
// Block b owns 64 consecutive idx of the G*DMID space; waves split the 200
// c-chunks 4 ways (50 each), LDS-combine, then +b2, relu.
__global__ __launch_bounds__(256) void gemm2_reduce(
    const float* __restrict__ partials, const float* __restrict__ b2,
    float* __restrict__ h2) {
  __shared__ float s_red[3][64];
  const int tid = threadIdx.x;
  const int li = tid & 63;   // idx offset within block
  const int w = tid >> 6;    // c-chunk 0..3
  const int idx = blockIdx.x * 64 + li;
  float s = 0.0f;
#pragma unroll 5
  for (int c = w * 50; c < w * 50 + 50; ++c)
    s += partials[(size_t)c * (G * DMID) + idx];
  if (w > 0) s_red[w - 1][li] = s;
  __syncthreads();
  if (w == 0) {
    s += s_red[0][li] + s_red[1][li] + s_red[2][li];
    h2[idx] = relu(s + b2[idx & 31]);
  }
}

// ---------------- K5: GEMM3 + cosine + squared error -> atomic mean ----------------
// Adds e^2/256 straight into out[0] (zeroed by w1prep). Replaces head+loss pair.
__global__ __launch_bounds__(256) void head_kernel(
    const float* __restrict__ h2, const float* __restrict__ W3,
    const float* __restrict__ b3, const float* __restrict__ ts,
    float* __restrict__ out) {
  __shared__ float sA[DMID], sB[DMID];
  __shared__ float rdot[4], rna[4], rnb[4];
  const int p = blockIdx.x;
  const int tid = threadIdx.x;
  if (tid < DMID) sA[tid] = h2[(size_t)(2 * p) * DMID + tid];
  else if (tid < 2 * DMID) sB[tid - DMID] = h2[(size_t)(2 * p + 1) * DMID + (tid - DMID)];
  __syncthreads();

  float dot = 0.0f, na = 0.0f, nb = 0.0f;
#pragma unroll
  for (int rep = 0; rep < 2; ++rep) {
    const int o = rep * 256 + tid;
    const float* w = W3 + (size_t)o * DMID;
    float accA = b3[o], accB = accA;
#pragma unroll
    for (int m = 0; m < DMID; m += 4) {
      const float4 wv = *(const float4*)&w[m];
      accA = fmaf(sA[m], wv.x, accA); accB = fmaf(sB[m], wv.x, accB);
      accA = fmaf(sA[m + 1], wv.y, accA); accB = fmaf(sB[m + 1], wv.y, accB);
      accA = fmaf(sA[m + 2], wv.z, accA); accB = fmaf(sB[m + 2], wv.z, accB);
      accA = fmaf(sA[m + 3], wv.w, accA); accB = fmaf(sB[m + 3], wv.w, accB);
    }
    const float a = relu(accA), b = relu(accB);
    dot = fmaf(a, b, dot); na = fmaf(a, a, na); nb = fmaf(b, b, nb);
  }
#pragma unroll
  for (int off = 32; off >= 1; off >>= 1) {
    dot += __shfl_down(dot, off);
    na  += __shfl_down(na, off);
    nb  += __shfl_down(nb, off);
  }
  const int wave = tid >> 6, lane = tid & 63;
  if (lane == 0) { rdot[wave] = dot; rna[wave] = na; rnb[wave] = nb; }
  __syncthreads();
  if (tid == 0) {
    const float dt = rdot[0] + rdot[1] + rdot[2] + rdot[3];
    const float nA = rna[0] + rna[1] + rna[2] + rna[3];
    const float nB = rnb[0] + rnb[1] + rnb[2] + rnb[3];
    const float n1 = fmaxf(sqrtf(nA), 1e-6f);
    const float n2 = fmaxf(sqrtf(nB), 1e-6f);
    const float sc = dt / (n1 * n2);
    const float e = sc - ts[p];
    gl_fadd(out, e * e * (1.0f / 256.0f));
  }
}

extern "C" void kernel_launch(void* const* d_in, const int* in_sizes, int n_in,
                              void* d_out, int out_size, void* d_ws, size_t ws_size,
                              hipStream_t stream) {
  const float* x       = (const float*)d_in[0];
  const int*   cluster = (const int*)d_in[1];
  const float* ts      = (const float*)d_in[2];
  const float* W1      = (const float*)d_in[3];
  const float* b1      = (const float*)d_in[4];
  const float* W2      = (const float*)d_in[5];
  const float* b2      = (const float*)d_in[6];
  const float* W3      = (const float*)d_in[7];
  const float* b3      = (const float*)d_in[8];

  float* ws = (float*)d_ws;
  float* h1        = ws;                                   // GK*D
  float* partials  = h1 + (size_t)GK * D;                  // NCHUNK*G*DMID
  float* h2        = partials + (size_t)NCHUNK * G * DMID; // G*DMID
  ushort* wfrag_hi = (ushort*)(h2 + (size_t)G * DMID);     // 16384 bf16
  ushort* wfrag_lo = wfrag_hi + 16384;                     // 16384 bf16
  float* out       = (float*)d_out;

  w1prep<<<65, 256, 0, stream>>>(W1, wfrag_hi, wfrag_lo, out);
  dim3 gridP(8, G);
  pool_gemm1_fused<<<gridP, 256, 0, stream>>>(x, cluster, wfrag_hi, wfrag_lo, b1, h1);
  dim3 gridC(NCHUNK, 16);
  gemm2_partial<<<gridC, 256, (32 * SH + 128 * SW2) * sizeof(float), stream>>>(h1, W2, partials);
  gemm2_reduce<<<G * DMID / 64, 256, 0, stream>>>(partials, b2, h2);
  head_kernel<<<G / 2, 256, 0, stream>>>(h2, W3, b3, ts, out);
}